// Round 1
// baseline (112644.824 us; speedup 1.0000x reference)
//
#include <hip/hip_runtime.h>
#include <hip/hip_bf16.h>
#include <cstdint>

typedef __attribute__((ext_vector_type(4))) float floatx4;
typedef __attribute__((ext_vector_type(8))) __bf16 bf16x8;
typedef __attribute__((ext_vector_type(4))) __bf16 bf16x4;

#define HID    1024
#define SEQ    4096
#define TGT    1024
#define ENC_T  3072
#define IN_DIM 544
#define NCLS   50000

// ---------------- embed: x = [emb_loc[loc] | emb_tim[tim]] ----------------
__global__ __launch_bounds__(128) void embed_kernel(
    const int* __restrict__ loc, const int* __restrict__ tim,
    const float* __restrict__ el, const float* __restrict__ et,
    float* __restrict__ x) {
  int row = blockIdx.x, t = threadIdx.x;
  int li = loc[row], ti = tim[row];
  float4 v = *(const float4*)(el + (size_t)li * 512 + t * 4);
  *(float4*)(x + (size_t)row * IN_DIM + t * 4) = v;
  if (t < 8) {
    float4 w = *(const float4*)(et + (size_t)ti * 32 + t * 4);
    *(float4*)(x + (size_t)row * IN_DIM + 512 + t * 4) = w;
  }
}

// ---------------- generic NT GEMM: C[M,N] = A[M,K] @ B[N,K]^T (+bias[n]) --
// fp32 inputs converted to bf16 while staging to LDS; MFMA 16x16x32 bf16.
// M % 128 == 0 assumed; N,K guarded (K % 32 == 0).
#define BK  64
#define LDT 72   // 64 + 8 bf16 pad; row stride 144 B (16-aligned)

__global__ __launch_bounds__(256) void gemm_nt(
    const float* __restrict__ A, int lda,
    const float* __restrict__ B, int ldb,
    float* __restrict__ C, int ldc,
    const float* __restrict__ bias,
    int M, int N, int K) {
  __shared__ __bf16 As[128 * LDT];
  __shared__ __bf16 Bs[128 * LDT];
  const int tid = threadIdx.x;
  const int bm = blockIdx.x * 128, bn = blockIdx.y * 128;
  const int wave = tid >> 6, lane = tid & 63;
  const int wm = (wave & 1) * 64, wn = (wave >> 1) * 64;
  const int fr = lane & 15;
  const int kq = (lane >> 4) * 8;

  floatx4 acc[4][4];
#pragma unroll
  for (int i = 0; i < 4; i++)
#pragma unroll
    for (int j = 0; j < 4; j++) acc[i][j] = (floatx4){0.f, 0.f, 0.f, 0.f};

  const int nkt = (K + BK - 1) / BK;
  for (int kt = 0; kt < nkt; ++kt) {
    const int k0 = kt * BK;
#pragma unroll
    for (int i = 0; i < 8; i++) {
      int flat = tid + i * 256;       // 2048 float4 slots: 128 rows x 16
      int r = flat >> 4;
      int c4 = (flat & 15) * 4;
      float4 va = {0, 0, 0, 0}, vb = {0, 0, 0, 0};
      if (k0 + c4 < K) {
        va = *(const float4*)(A + (size_t)(bm + r) * lda + k0 + c4);
        if (bn + r < N) vb = *(const float4*)(B + (size_t)(bn + r) * ldb + k0 + c4);
      }
      *(bf16x4*)(As + r * LDT + c4) =
          (bf16x4){(__bf16)va.x, (__bf16)va.y, (__bf16)va.z, (__bf16)va.w};
      *(bf16x4*)(Bs + r * LDT + c4) =
          (bf16x4){(__bf16)vb.x, (__bf16)vb.y, (__bf16)vb.z, (__bf16)vb.w};
    }
    __syncthreads();
#pragma unroll
    for (int kh = 0; kh < 2; ++kh) {
      const int kf = kh * 32 + kq;
      bf16x8 af[4], bfr[4];
#pragma unroll
      for (int i = 0; i < 4; i++) {
        af[i]  = *(const bf16x8*)(As + (wm + i * 16 + fr) * LDT + kf);
        bfr[i] = *(const bf16x8*)(Bs + (wn + i * 16 + fr) * LDT + kf);
      }
#pragma unroll
      for (int mi = 0; mi < 4; mi++)
#pragma unroll
        for (int ni = 0; ni < 4; ni++)
          acc[mi][ni] = __builtin_amdgcn_mfma_f32_16x16x32_bf16(
              af[mi], bfr[ni], acc[mi][ni], 0, 0, 0);
    }
    __syncthreads();
  }

  // epilogue: D[m = 4*(lane>>4)+r][n = lane&15]  (m89-verified layout)
  const int em = (lane >> 4) * 4;
#pragma unroll
  for (int mi = 0; mi < 4; mi++) {
#pragma unroll
    for (int ni = 0; ni < 4; ni++) {
      int gn = bn + wn + ni * 16 + fr;
      if (gn < N) {
        float bv = bias ? bias[gn] : 0.f;
        int gm = bm + wm + mi * 16 + em;
#pragma unroll
        for (int r2 = 0; r2 < 4; r2++)
          C[(size_t)(gm + r2) * ldc + gn] = acc[mi][ni][r2] + bv;
      }
    }
  }
}

// ---------------- persistent GRU scan (enc: WG 0..127, dec: WG 128..255) --
// Each WG owns 8 h-elements; 24 Whh rows cached in LDS as packed bf16x2.
// Inter-WG sync: double-buffered h in global + agent-scope flags.
#define SC_WGS 128

__global__ __launch_bounds__(256) void scan_kernel(
    const float* __restrict__ Whh_e, const float* __restrict__ bhh_e, const float* __restrict__ gi_e,
    const float* __restrict__ Whh_d, const float* __restrict__ bhh_d, const float* __restrict__ gi_d,
    float* __restrict__ Hh, float* __restrict__ HhT, float* __restrict__ outcat,
    float* __restrict__ hbuf_e, float* __restrict__ hbuf_d, int* __restrict__ flags) {
  const bool enc = blockIdx.x < SC_WGS;
  const int wid = enc ? blockIdx.x : (blockIdx.x - SC_WGS);
  const int T = enc ? ENC_T : TGT;
  const float* Whh = enc ? Whh_e : Whh_d;
  const float* bhh = enc ? bhh_e : bhh_d;
  const float* gi  = enc ? gi_e : gi_d;
  float* hbuf = enc ? hbuf_e : hbuf_d;
  int* myflags = flags + (enc ? 0 : SC_WGS);

  __shared__ unsigned int wlds[24 * 512];  // 48 KB: [e_local(8)][gate(3)][k2(512)]
  const int tid = threadIdx.x;

  // preload weights (fp32 -> packed bf16x2)
  for (int i = tid; i < 24 * 512; i += 256) {
    int el = i / (3 * 512);
    int rem = i - el * 3 * 512;
    int gate = rem >> 9;
    int k2 = rem & 511;
    int grow = gate * HID + wid * 8 + el;
    float2 w = *(const float2*)(Whh + (size_t)grow * HID + 2 * k2);
    unsigned short lo = __builtin_bit_cast(unsigned short, (__bf16)w.x);
    unsigned short hi = __builtin_bit_cast(unsigned short, (__bf16)w.y);
    wlds[i] = (unsigned int)lo | ((unsigned int)hi << 16);
  }
  __syncthreads();

  const int g = tid >> 5;    // group 0..7 -> h element
  const int sg = tid & 31;   // lane within group
  const int e = wid * 8 + g;
  const int lane = tid & 63;
  const int gl = tid & 32;   // group base lane within wave

  float bq = 0.f;
  if (sg < 3) bq = bhh[sg * HID + e];

  const unsigned int* wr = wlds + (g * 3 + 0) * 512;
  const unsigned int* wz = wlds + (g * 3 + 1) * 512;
  const unsigned int* wn = wlds + (g * 3 + 2) * 512;

  for (int t = 0; t < T; ++t) {
    float gval = 0.f;                    // prefetch input gates (flag-independent)
    if (sg < 3) gval = gi[(size_t)t * 3072 + sg * HID + e];

    if (t > 0) {
      long bail = 0;
      for (;;) {
        int f0 = __hip_atomic_load(&myflags[lane], __ATOMIC_ACQUIRE, __HIP_MEMORY_SCOPE_AGENT);
        int f1 = __hip_atomic_load(&myflags[lane + 64], __ATOMIC_ACQUIRE, __HIP_MEMORY_SCOPE_AGENT);
        if (__all(f0 >= t && f1 >= t)) break;
        if (++bail > (1L << 28)) break;  // safety valve against hangs
        __builtin_amdgcn_s_sleep(1);
      }
    }
    const float* hprev = hbuf + ((t + 1) & 1) * HID;
    float ar = 0.f, az = 0.f, an = 0.f;
#pragma unroll
    for (int j = 0; j < 16; ++j) {
      int k2 = sg + j * 32;
      float2 h2 = *(const float2*)(hprev + 2 * k2);
      unsigned int u;
      u = wr[k2];
      ar += __builtin_bit_cast(float, u << 16) * h2.x +
            __builtin_bit_cast(float, u & 0xffff0000u) * h2.y;
      u = wz[k2];
      az += __builtin_bit_cast(float, u << 16) * h2.x +
            __builtin_bit_cast(float, u & 0xffff0000u) * h2.y;
      u = wn[k2];
      an += __builtin_bit_cast(float, u << 16) * h2.x +
            __builtin_bit_cast(float, u & 0xffff0000u) * h2.y;
    }
#pragma unroll
    for (int o = 16; o; o >>= 1) {
      ar += __shfl_xor(ar, o);
      az += __shfl_xor(az, o);
      an += __shfl_xor(an, o);
    }
    float i_r = __shfl(gval, gl + 0);
    float i_z = __shfl(gval, gl + 1);
    float i_n = __shfl(gval, gl + 2);
    float b_r = __shfl(bq, gl + 0);
    float b_z = __shfl(bq, gl + 1);
    float b_n = __shfl(bq, gl + 2);
    if (sg == 0) {
      float r = 1.f / (1.f + expf(-(i_r + ar + b_r)));
      float z = 1.f / (1.f + expf(-(i_z + az + b_z)));
      float nn = tanhf(i_n + r * (an + b_n));
      float hnew = (1.f - z) * nn + z * hprev[e];
      hbuf[(t & 1) * HID + e] = hnew;
      if (enc) {
        Hh[(size_t)t * HID + e] = hnew;
        HhT[(size_t)e * ENC_T + t] = hnew;
      } else {
        outcat[(size_t)t * 2048 + e] = hnew;  // hidden_state into out-concat cols 0..1023
      }
    }
    __threadfence();
    __syncthreads();
    if (tid == 0)
      __hip_atomic_store(&myflags[wid], t + 1, __ATOMIC_RELEASE, __HIP_MEMORY_SCOPE_AGENT);
  }
}

// ---------------- reductions ----------------
__device__ __forceinline__ float wave_max(float v) {
#pragma unroll
  for (int o = 32; o; o >>= 1) v = fmaxf(v, __shfl_xor(v, o));
  return v;
}
__device__ __forceinline__ float wave_sum(float v) {
#pragma unroll
  for (int o = 32; o; o >>= 1) v += __shfl_xor(v, o);
  return v;
}

// in-place row softmax over [TGT, ENC_T]
__global__ __launch_bounds__(256) void softmax_kernel(float* __restrict__ E) {
  __shared__ float red[4];
  int row = blockIdx.x;
  float* p = E + (size_t)row * ENC_T;
  int tid = threadIdx.x, wave = tid >> 6;
  float v[12];
  float m = -3.4e38f;
#pragma unroll
  for (int j = 0; j < 12; j++) { v[j] = p[tid + j * 256]; m = fmaxf(m, v[j]); }
  m = wave_max(m);
  if ((tid & 63) == 0) red[wave] = m;
  __syncthreads();
  m = fmaxf(fmaxf(red[0], red[1]), fmaxf(red[2], red[3]));
  __syncthreads();
  float s = 0.f;
#pragma unroll
  for (int j = 0; j < 12; j++) { v[j] = expf(v[j] - m); s += v[j]; }
  s = wave_sum(s);
  if ((tid & 63) == 0) red[wave] = s;
  __syncthreads();
  s = red[0] + red[1] + red[2] + red[3];
  float inv = 1.f / s;
#pragma unroll
  for (int j = 0; j < 12; j++) p[tid + j * 256] = v[j] * inv;
}

__global__ __launch_bounds__(256) void lse_kernel(const float* __restrict__ Y,
                                                  float* __restrict__ lse) {
  __shared__ float red[4];
  int row = blockIdx.x;
  const float* p = Y + (size_t)row * NCLS;
  int tid = threadIdx.x, wave = tid >> 6;
  float m = -3.4e38f;
  for (int c = tid; c < NCLS; c += 256) m = fmaxf(m, p[c]);
  m = wave_max(m);
  if ((tid & 63) == 0) red[wave] = m;
  __syncthreads();
  m = fmaxf(fmaxf(red[0], red[1]), fmaxf(red[2], red[3]));
  __syncthreads();
  float s = 0.f;
  for (int c = tid; c < NCLS; c += 256) s += expf(p[c] - m);
  s = wave_sum(s);
  if ((tid & 63) == 0) red[wave] = s;
  __syncthreads();
  if (tid == 0) lse[row] = m + logf(red[0] + red[1] + red[2] + red[3]);
}

__global__ __launch_bounds__(256) void sub_kernel(float* __restrict__ Y,
                                                  const float* __restrict__ lse) {
  const unsigned total = (unsigned)TGT * (NCLS / 4);
  unsigned stride = gridDim.x * 256;
  for (unsigned i = blockIdx.x * 256 + threadIdx.x; i < total; i += stride) {
    unsigned row = i / (NCLS / 4);
    float l = lse[row];
    float4 v = ((float4*)Y)[i];
    v.x -= l; v.y -= l; v.z -= l; v.w -= l;
    ((float4*)Y)[i] = v;
  }
}

// ---------------- launch ----------------
extern "C" void kernel_launch(void* const* d_in, const int* in_sizes, int n_in,
                              void* d_out, int out_size, void* d_ws, size_t ws_size,
                              hipStream_t stream) {
  const int*   loc     = (const int*)d_in[0];
  const int*   tim     = (const int*)d_in[1];
  // d_in[2] = target_len (fixed 1024, ignored)
  const float* emb_loc = (const float*)d_in[3];
  const float* emb_tim = (const float*)d_in[4];
  const float* Wih_e   = (const float*)d_in[5];
  const float* Whh_e   = (const float*)d_in[6];
  const float* bih_e   = (const float*)d_in[7];
  const float* bhh_e   = (const float*)d_in[8];
  const float* Wih_d   = (const float*)d_in[9];
  const float* Whh_d   = (const float*)d_in[10];
  const float* bih_d   = (const float*)d_in[11];
  const float* bhh_d   = (const float*)d_in[12];
  const float* W_fc    = (const float*)d_in[13];
  const float* b_fc    = (const float*)d_in[14];
  float* out = (float*)d_out;

  float* ws = (float*)d_ws;
  int*   flags  = (int*)ws;                       // 256 ints
  float* hbuf_e = ws + 256;                       // 2*1024
  float* hbuf_d = ws + 256 + 2048;                // 2*1024
  float* lse    = ws + 256 + 4096;                // 1024
  float* x      = ws + 5376;                      // 4096*544
  float* gi_e   = x + (size_t)SEQ * IN_DIM;       // 3072*3072
  float* gi_d   = gi_e + (size_t)ENC_T * 3072;    // 1024*3072
  float* Hh     = gi_d + (size_t)TGT * 3072;      // 3072*1024
  float* HhT    = Hh + (size_t)ENC_T * HID;       // 1024*3072
  float* outcat = HhT + (size_t)HID * ENC_T;      // 1024*2048
  float* energ  = outcat + (size_t)TGT * 2048;    // 1024*3072 (attn in-place)

  // zero sync flags + h double-buffers (ws is poisoned before each launch)
  hipMemsetAsync(d_ws, 0, (256 + 4096) * sizeof(float), stream);

  embed_kernel<<<SEQ, 128, 0, stream>>>(loc, tim, emb_loc, emb_tim, x);

  // input-gate precompute: gi = x @ Wih^T + bih
  gemm_nt<<<dim3(ENC_T / 128, 3072 / 128), 256, 0, stream>>>(
      x, IN_DIM, Wih_e, IN_DIM, gi_e, 3072, bih_e, ENC_T, 3072, IN_DIM);
  gemm_nt<<<dim3(TGT / 128, 3072 / 128), 256, 0, stream>>>(
      x + (size_t)ENC_T * IN_DIM, IN_DIM, Wih_d, IN_DIM, gi_d, 3072, bih_d, TGT, 3072, IN_DIM);

  // sequential GRU scans (encoder + decoder concurrently)
  scan_kernel<<<2 * SC_WGS, 256, 0, stream>>>(Whh_e, bhh_e, gi_e, Whh_d, bhh_d, gi_d,
                                              Hh, HhT, outcat, hbuf_e, hbuf_d, flags);

  // energies = Hs @ Hh^T
  gemm_nt<<<dim3(TGT / 128, ENC_T / 128), 256, 0, stream>>>(
      outcat, 2048, Hh, HID, energ, ENC_T, nullptr, TGT, ENC_T, HID);
  softmax_kernel<<<TGT, 256, 0, stream>>>(energ);
  // context = attn @ Hh  (= attn @ (Hh^T)^T), written into outcat cols 1024..2047
  gemm_nt<<<dim3(TGT / 128, HID / 128), 256, 0, stream>>>(
      energ, ENC_T, HhT, ENC_T, outcat + HID, 2048, nullptr, TGT, HID, ENC_T);

  // y = outcat @ W_fc^T + b_fc
  gemm_nt<<<dim3(TGT / 128, (NCLS + 127) / 128), 256, 0, stream>>>(
      outcat, 2048, W_fc, 2048, out, NCLS, b_fc, TGT, NCLS, 2048);

  // log_softmax
  lse_kernel<<<TGT, 256, 0, stream>>>(out, lse);
  sub_kernel<<<4096, 256, 0, stream>>>(out, lse);
}